// Round 18
// baseline (114.662 us; speedup 1.0000x reference)
//
#include <hip/hip_runtime.h>
#include <hip/hip_bf16.h>

// Problem constants: B=8, N=8192, S=2048, C1=128, C2=256, OUT=256
#define BB   8
#define NN   8192
#define SS   2048
#define C1C  128
#define C2C  256
#define KIN  384
#define OUTC 256

typedef __attribute__((ext_vector_type(4))) float f32x4;
typedef __attribute__((ext_vector_type(8))) short short8;
typedef __attribute__((ext_vector_type(8))) unsigned short ushortx8;

__device__ __forceinline__ ushort f2bf(float v) {
    __hip_bfloat16 h = __float2bfloat16(v);
    return __builtin_bit_cast(ushort, h);
}

__device__ __forceinline__ float med3(float a, float b, float c) {
    return __builtin_amdgcn_fmed3f(a, b, c);
}

// ---------------------------------------------------------------------------
// Fused 3-NN scan + gather, Q=4 queries per thread (NEW), L=32 lanes/query.
// Rationale: total LDS wave-instructions = 2*2048*65536/(64*Q) — only Q
// shrinks the shared per-CU LDS-pipe load. Q=4 halves it vs r13's Q=2
// while VALU ops/eval stay identical (two-pass med3 selection is branchless
// in pass 1 — r7's Q=4 failure came from its 14-op cndmask insert, absent
// here). r17's pk_fma inline-asm reverted (broke compiler scheduling).
// 1024 threads, 128 queries/block, 512 blocks = 2 blocks/CU = 8 waves/SIMD.
// Selection: lane-local strict < on monotone index stream + cross-lane lex
// (f,idx) merge == stable lax.top_k (partition-invariant).
// ---------------------------------------------------------------------------
__global__ __launch_bounds__(1024, 8) void knn_gather_kernel(
    const float* __restrict__ xyz1, const float* __restrict__ xyz2,
    const float* __restrict__ feat2, ushort* __restrict__ interpB)
{
    __shared__ float4 sp[SS];                     // 32 KB
    __shared__ int   sIdx[128][3];
    __shared__ float sW[128][3];

    const int tid   = threadIdx.x;
    const int b     = blockIdx.x & 7;             // XCD-aligned batch
    const int chunk = blockIdx.x >> 3;            // 0..63
    const int qbase = chunk << 7;                 // 128 queries per block

    const float* x2 = xyz2 + (size_t)b * SS * 3;
    for (int i = tid; i < SS; i += 1024) {
        float x = x2[i*3+0], y = x2[i*3+1], z = x2[i*3+2];
        sp[i] = make_float4(-2.f*x, -2.f*y, -2.f*z, x*x + y*y + z*z);
    }
    __syncthreads();

    const int g = tid >> 5;                       // 0..31 (query quad)
    const int l = tid & 31;                       // lane within query
    const int q0 = qbase + g * 4;

    // 4 consecutive query rows = 48B contiguous -> 3x float4 (16B-aligned)
    const float* qp = xyz1 + ((size_t)b * NN + q0) * 3;
    float4 qa = ((const float4*)qp)[0];
    float4 qb = ((const float4*)qp)[1];
    float4 qc = ((const float4*)qp)[2];
    float px[4] = {qa.x, qa.w, qb.z, qc.y};
    float py[4] = {qa.y, qb.x, qb.w, qc.z};
    float pz[4] = {qa.z, qb.y, qc.x, qc.w};

    // ---------------- pass 1: top-3 values, branchless ----------------
    float c0[4], c1[4], c2[4];
#pragma unroll
    for (int qi = 0; qi < 4; ++qi) { c0[qi] = c1[qi] = c2[qi] = 1e30f; }

    for (int jj = 0; jj < 64; jj += 2) {
        float4 P[2];
#pragma unroll
        for (int u = 0; u < 2; ++u) P[u] = sp[((jj + u) << 5) + l];
#pragma unroll
        for (int u = 0; u < 2; ++u) {
#pragma unroll
            for (int qi = 0; qi < 4; ++qi) {
                float f = fmaf(px[qi], P[u].x,
                          fmaf(py[qi], P[u].y,
                          fmaf(pz[qi], P[u].z, P[u].w)));
                c2[qi] = med3(f, c1[qi], c2[qi]);
                c1[qi] = med3(f, c0[qi], c1[qi]);
                c0[qi] = fminf(f, c0[qi]);
            }
        }
    }

    // value-merge across the 32-lane group (multiset union top-3)
#pragma unroll
    for (int m = 1; m <= 16; m <<= 1) {
#pragma unroll
        for (int qi = 0; qi < 4; ++qi) {
            float b0 = __shfl_xor(c0[qi], m);
            float b1 = __shfl_xor(c1[qi], m);
            float b2 = __shfl_xor(c2[qi], m);
            float bv[3] = {b0, b1, b2};
#pragma unroll
            for (int e = 0; e < 3; ++e) {
                float d = bv[e];
                c2[qi] = med3(d, c1[qi], c2[qi]);
                c1[qi] = med3(d, c0[qi], c1[qi]);
                c0[qi] = fminf(d, c0[qi]);
            }
        }
    }
    float t[4];
#pragma unroll
    for (int qi = 0; qi < 4; ++qi) t[qi] = c2[qi];  // exact 3rd-smallest

    // ---------------- pass 2: index recovery (rare inserts) ----------------
    float e0[4], e1[4], e2[4];
    int   i0[4], i1[4], i2[4];
#pragma unroll
    for (int qi = 0; qi < 4; ++qi) {
        e0[qi] = e1[qi] = e2[qi] = 1e30f;
        i0[qi] = i1[qi] = i2[qi] = 0x3fffffff;
    }

    for (int jj = 0; jj < 64; jj += 2) {
        float4 P[2];
#pragma unroll
        for (int u = 0; u < 2; ++u) P[u] = sp[((jj + u) << 5) + l];
#pragma unroll
        for (int u = 0; u < 2; ++u) {
            const int s = ((jj + u) << 5) + l;
#pragma unroll
            for (int qi = 0; qi < 4; ++qi) {
                float f = fmaf(px[qi], P[u].x,
                          fmaf(py[qi], P[u].y,
                          fmaf(pz[qi], P[u].z, P[u].w)));
                if (f <= t[qi]) {                  // ~3 hits per query total
                    bool lt2 = (f < e2[qi]) || (f == e2[qi] && s < i2[qi]);
                    if (lt2) {
                        bool lt1 = (f < e1[qi]) || (f == e1[qi] && s < i1[qi]);
                        bool lt0 = (f < e0[qi]) || (f == e0[qi] && s < i0[qi]);
                        e2[qi] = lt1 ? e1[qi] : f;  i2[qi] = lt1 ? i1[qi] : s;
                        e1[qi] = lt0 ? e0[qi] : (lt1 ? f : e1[qi]);
                        i1[qi] = lt0 ? i0[qi] : (lt1 ? s : i1[qi]);
                        e0[qi] = lt0 ? f : e0[qi];  i0[qi] = lt0 ? s : i0[qi];
                    }
                }
            }
        }
    }

    // lex merge across the 32-lane group
#pragma unroll
    for (int m = 1; m <= 16; m <<= 1) {
#pragma unroll
        for (int qi = 0; qi < 4; ++qi) {
            float ob0 = __shfl_xor(e0[qi], m), ob1 = __shfl_xor(e1[qi], m), ob2 = __shfl_xor(e2[qi], m);
            int   oj0 = __shfl_xor(i0[qi], m), oj1 = __shfl_xor(i1[qi], m), oj2 = __shfl_xor(i2[qi], m);
            float dv[3] = {ob0, ob1, ob2}; int iv[3] = {oj0, oj1, oj2};
#pragma unroll
            for (int e = 0; e < 3; ++e) {
                float d = dv[e]; int s = iv[e];
                bool lt2 = (d < e2[qi]) || (d == e2[qi] && s < i2[qi]);
                if (lt2) {
                    bool lt1 = (d < e1[qi]) || (d == e1[qi] && s < i1[qi]);
                    bool lt0 = (d < e0[qi]) || (d == e0[qi] && s < i0[qi]);
                    e2[qi] = lt1 ? e1[qi] : d;  i2[qi] = lt1 ? i1[qi] : s;
                    e1[qi] = lt0 ? e0[qi] : (lt1 ? d : e1[qi]);
                    i1[qi] = lt0 ? i0[qi] : (lt1 ? s : i1[qi]);
                    e0[qi] = lt0 ? d : e0[qi];  i0[qi] = lt0 ? s : i0[qi];
                }
            }
        }
    }

    if (l == 0) {
#pragma unroll
        for (int qi = 0; qi < 4; ++qi) {
            float nx = px[qi], ny = py[qi], nz = pz[qi];
            float n1 = nx*nx + ny*ny + nz*nz;
            float d0 = sqrtf(fmaxf(n1 + e0[qi], 0.f));
            float d1 = sqrtf(fmaxf(n1 + e1[qi], 0.f));
            float d2s = sqrtf(fmaxf(n1 + e2[qi], 0.f));
            float w0 = 1.f / fmaxf(d0, 1e-10f);
            float w1 = 1.f / fmaxf(d1, 1e-10f);
            float w2 = 1.f / fmaxf(d2s, 1e-10f);
            float wsum = w0 + w1 + w2;
            int qq = g * 4 + qi;
            sIdx[qq][0] = i0[qi]; sIdx[qq][1] = i1[qi]; sIdx[qq][2] = i2[qi];
            sW[qq][0] = w0 / wsum; sW[qq][1] = w1 / wsum; sW[qq][2] = w2 / wsum;
        }
    }
    __syncthreads();

    // gather phase: wave wid handles queries wid, wid+16, ... (coalesced rows)
    const int wid = tid >> 6, lane = tid & 63;
    for (int qq = wid; qq < 128; qq += 16) {
        int a0 = sIdx[qq][0], a1 = sIdx[qq][1], a2 = sIdx[qq][2];
        float w0 = sW[qq][0], w1 = sW[qq][1], w2 = sW[qq][2];
        const float4* r0 = (const float4*)(feat2 + ((size_t)b * SS + a0) * C2C);
        const float4* r1 = (const float4*)(feat2 + ((size_t)b * SS + a1) * C2C);
        const float4* r2 = (const float4*)(feat2 + ((size_t)b * SS + a2) * C2C);
        float4 v0 = r0[lane], v1 = r1[lane], v2 = r2[lane];
        ushort4 o;
        o.x = f2bf(w0*v0.x + w1*v1.x + w2*v2.x);
        o.y = f2bf(w0*v0.y + w1*v1.y + w2*v2.y);
        o.z = f2bf(w0*v0.z + w1*v1.z + w2*v2.z);
        o.w = f2bf(w0*v0.w + w1*v1.w + w2*v2.w);
        *(ushort4*)(interpB + ((size_t)b * NN + qbase + qq) * C2C + lane * 4) = o;
    }
}

// ---------------------------------------------------------------------------
// Weight prep: W1t (N-major transpose) + W2pack (fragment-packed, r16).
// ---------------------------------------------------------------------------
__global__ __launch_bounds__(256) void weights_prep_kernel(
    const float* __restrict__ W1, ushort* __restrict__ W1t,
    const float* __restrict__ W2, ushort* __restrict__ W2pack)
{
    int idx = blockIdx.x * 256 + threadIdx.x;
    const int n1 = KIN * OUTC;                    // 98304
    if (idx < n1) {
        int n = idx / KIN, k = idx - n * KIN;
        W1t[idx] = f2bf(W1[(size_t)k * OUTC + n]);
    } else {
        int o = idx - n1;
        if (o < OUTC * OUTC) {
            int e = o & 7, lane = (o >> 3) & 63, j = (o >> 9) & 3;
            int wc = (o >> 11) & 3, s = o >> 13;
            int n = wc * 64 + j * 16 + (lane & 15);
            int k = s * 32 + (lane >> 4) * 8 + e;
            W2pack[o] = f2bf(W2[(size_t)k * OUTC + n]);
        }
    }
}

// ---------------------------------------------------------------------------
// FUSED two-layer MFMA GEMM (EXACT r16, measured best):
//   out = relu(relu([feat1|interpB]@W1^T + b1)@W2^T + b2), H in LDS only.
// Phase 1: dbuf staged A+W1t (1 barrier/K-step). Phase 2: register-B from
// W2pack (contiguous 1KB bursts, 1-step prefetch), barrier-free.
// ---------------------------------------------------------------------------
#define GBM 128
#define GBN 256
#define GBK 32

__device__ __forceinline__ void gld_lds16(const void* g, void* l) {
    __builtin_amdgcn_global_load_lds(
        (const __attribute__((address_space(1))) void*)g,
        (__attribute__((address_space(3))) void*)l, 16, 0, 0);
}

__global__ __launch_bounds__(512, 4) void gemm_fused(
    const float* __restrict__ feat1,
    const ushort* __restrict__ interpB,
    const ushort* __restrict__ W1t, const float* __restrict__ b1,
    const ushort* __restrict__ W2pack, const float* __restrict__ b2,
    float* __restrict__ out)
{
    __shared__ ushort pool[GBM * 256];   // 64 KB: phase1 dbuf (2x24KB); then H

    const int tid  = threadIdx.x;
    const int lane = tid & 63;
    const int wid  = tid >> 6;           // 0..7
    const int m0   = blockIdx.x * GBM;
    const int wr   = wid >> 2;           // 0..1
    const int wc   = wid & 3;            // 0..3

    const int rsub = lane >> 2;                    // 0..15 (row in 16-row chunk)
    const int slot = lane & 3;                     // 0..3  (8-ushort slot)
    const int csub = slot * 8;                     // linear LDS slot offset
    const int usw  = (slot ^ (rsub & 3)) * 8;      // swizzled SOURCE slot offset

    const int kgrp = (lane >> 4) * 8;
    const int rl   = lane & 15;
    const int ksw  = kgrp ^ ((rl & 3) << 3);       // swizzled read slot
    const int cl   = lane & 15;
    const int rgrp = (lane >> 4) * 4;

    // stage one K-step of A (8 chunks) + W1t (16 chunks) into buffer `buf`.
    auto stageAB = [&](int k0, int buf) {
        ushort* sAb = pool + buf * 12288;          // 8KB A
        ushort* sBb = sAb + 4096;                  // 16KB B
#pragma unroll
        for (int c = 0; c < 3; ++c) {
            const int cid = wid * 3 + c;           // 0..23
            if (cid < 8) {
                const int r = m0 + cid * 16 + rsub;
                if (k0 < C1C) {
                    const float* src = feat1 + (size_t)r * C1C + k0 + usw;
                    float4 u = ((const float4*)src)[0];
                    float4 v = ((const float4*)src)[1];
                    ushortx8 t;
                    t[0] = f2bf(u.x); t[1] = f2bf(u.y); t[2] = f2bf(u.z); t[3] = f2bf(u.w);
                    t[4] = f2bf(v.x); t[5] = f2bf(v.y); t[6] = f2bf(v.z); t[7] = f2bf(v.w);
                    *(ushortx8*)&sAb[cid * 512 + rsub * 32 + csub] = t;
                } else {
                    gld_lds16(interpB + (size_t)r * C2C + (k0 - C1C) + usw, &sAb[cid * 512]);
                }
            } else {
                const int bi = cid - 8;
                const int r = bi * 16 + rsub;
                gld_lds16(W1t + (size_t)r * KIN + k0 + usw, &sBb[bi * 512]);
            }
        }
    };

    // ---------------- phase 1: acc1 = A @ W1t^T (double-buffered) ----------
    f32x4 acc1[4][4];
#pragma unroll
    for (int i = 0; i < 4; ++i)
#pragma unroll
        for (int j = 0; j < 4; ++j) acc1[i][j] = (f32x4){0.f, 0.f, 0.f, 0.f};

    int cur = 0;
    stageAB(0, 0);
    for (int k0 = 0; k0 < KIN; k0 += GBK) {
        __syncthreads();                 // stage(k0->cur) done; prev reads done
        if (k0 + GBK < KIN) stageAB(k0 + GBK, cur ^ 1);

        const ushort* sAb = pool + cur * 12288;
        const ushort* sBb = sAb + 4096;
        short8 af[4], bf[4];
#pragma unroll
        for (int i = 0; i < 4; ++i) {
            af[i] = *(const short8*)&sAb[(wr * 64 + i * 16 + rl) * GBK + ksw];
            bf[i] = *(const short8*)&sBb[(wc * 64 + i * 16 + rl) * GBK + ksw];
        }
#pragma unroll
        for (int i = 0; i < 4; ++i)
#pragma unroll
            for (int j = 0; j < 4; ++j)
                acc1[i][j] = __builtin_amdgcn_mfma_f32_16x16x32_bf16(
                    af[i], bf[j], acc1[i][j], 0, 0, 0);
        cur ^= 1;
    }
    __syncthreads();                     // all phase-1 LDS reads done (pool reuse)

    // issue phase-2 first B-frags early (hide L2 latency under H writes)
    short8 bfc[4], bfn[4];
#pragma unroll
    for (int j = 0; j < 4; ++j)
        bfc[j] = *(const short8*)&W2pack[(size_t)(0 * 16 + wc * 4 + j) * 512 + lane * 8];

    // ---------------- transition: H = relu(acc1+b1) -> LDS (bf16) ----------
#pragma unroll
    for (int j = 0; j < 4; ++j) {
        const int c = wc * 64 + j * 16 + cl;
        const float bv = b1[c];
        const int u = c >> 3, sub = c & 7;
#pragma unroll
        for (int i = 0; i < 4; ++i) {
#pragma unroll
            for (int rr = 0; rr < 4; ++rr) {
                const int r = wr * 64 + i * 16 + rgrp + rr;
                const float v = fmaxf(acc1[i][j][rr] + bv, 0.f);
                pool[r * 256 + ((u ^ (r & 31)) << 3) + sub] = f2bf(v);
            }
        }
    }
    __syncthreads();                     // H complete

    // ---------------- phase 2: out = relu(H @ W2^T + b2), barrier-free -----
    f32x4 acc2[4][4];
#pragma unroll
    for (int i = 0; i < 4; ++i)
#pragma unroll
        for (int j = 0; j < 4; ++j) acc2[i][j] = (f32x4){0.f, 0.f, 0.f, 0.f};

    for (int s = 0; s < 8; ++s) {
        if (s < 7) {
#pragma unroll
            for (int j = 0; j < 4; ++j)
                bfn[j] = *(const short8*)&W2pack[(size_t)((s + 1) * 16 + wc * 4 + j) * 512 + lane * 8];
        }
        const int ub = s * 4 + (lane >> 4);        // H unit index 0..31
        short8 af[4];
#pragma unroll
        for (int i = 0; i < 4; ++i) {
            const int r = wr * 64 + i * 16 + rl;
            af[i] = *(const short8*)&pool[r * 256 + ((ub ^ (r & 31)) << 3)];
        }
#pragma unroll
        for (int i = 0; i < 4; ++i)
#pragma unroll
            for (int j = 0; j < 4; ++j)
                acc2[i][j] = __builtin_amdgcn_mfma_f32_16x16x32_bf16(
                    af[i], bfc[j], acc2[i][j], 0, 0, 0);
#pragma unroll
        for (int j = 0; j < 4; ++j) bfc[j] = bfn[j];
    }

    // ---------------- epilogue: bias + relu -> f32 out ---------------------
#pragma unroll
    for (int j = 0; j < 4; ++j) {
        const int col = wc * 64 + j * 16 + cl;
        const float bv = b2[col];
#pragma unroll
        for (int i = 0; i < 4; ++i) {
            const int rowb = m0 + wr * 64 + i * 16 + rgrp;
#pragma unroll
            for (int rr = 0; rr < 4; ++rr) {
                out[(size_t)(rowb + rr) * OUTC + col] =
                    fmaxf(acc2[i][j][rr] + bv, 0.f);
            }
        }
    }
}

// ---------------------------------------------------------------------------
// ws layout (bytes): interpB 33.5M @0 | W1t @33554432 | W2pack @33751040
// ---------------------------------------------------------------------------
extern "C" void kernel_launch(void* const* d_in, const int* in_sizes, int n_in,
                              void* d_out, int out_size, void* d_ws, size_t ws_size,
                              hipStream_t stream) {
    const float* xyz1  = (const float*)d_in[0];
    const float* xyz2  = (const float*)d_in[1];
    const float* feat1 = (const float*)d_in[2];
    const float* feat2 = (const float*)d_in[3];
    const float* W1    = (const float*)d_in[4];
    const float* b1    = (const float*)d_in[5];
    const float* W2    = (const float*)d_in[6];
    const float* b2    = (const float*)d_in[7];
    float* out = (float*)d_out;

    char* ws = (char*)d_ws;
    ushort* interpB = (ushort*)(ws);
    ushort* W1t     = (ushort*)(ws + 33554432);
    ushort* W2pack  = (ushort*)(ws + 33751040);

    const int M = BB * NN;  // 65536

    weights_prep_kernel<<<(KIN * OUTC + OUTC * OUTC + 255) / 256, 256, 0, stream>>>(
        W1, W1t, W2, W2pack);

    knn_gather_kernel<<<512, 1024, 0, stream>>>(xyz1, xyz2, feat2, interpB);

    gemm_fused<<<M / GBM, 512, 0, stream>>>(feat1, interpB,
                                            W1t, b1, W2pack, b2, out);
}

// Round 19
// 102.017 us; speedup vs baseline: 1.1239x; 1.1239x over previous
//
#include <hip/hip_runtime.h>
#include <hip/hip_bf16.h>

// Problem constants: B=8, N=8192, S=2048, C1=128, C2=256, OUT=256
#define BB   8
#define NN   8192
#define SS   2048
#define C1C  128
#define C2C  256
#define KIN  384
#define OUTC 256

typedef __attribute__((ext_vector_type(4))) float f32x4;
typedef __attribute__((ext_vector_type(8))) short short8;
typedef __attribute__((ext_vector_type(8))) unsigned short ushortx8;

__device__ __forceinline__ ushort f2bf(float v) {
    __hip_bfloat16 h = __float2bfloat16(v);
    return __builtin_bit_cast(ushort, h);
}

__device__ __forceinline__ float med3(float a, float b, float c) {
    return __builtin_amdgcn_fmed3f(a, b, c);
}

// ---------------------------------------------------------------------------
// Fused 3-NN scan + gather — EXACT r13/r16 scan structure (measured 65.5us,
// the robust floor across 6 variants: Q=2, L=16, u=4, two-pass med3).
// NEW (only change): weights prep folded in — 1 guarded element per thread
// (163,840 elems over 512x1024 threads), issued after sp staging so the
// global load/store latency overlaps the staging barrier. Saves one launch.
// 1024 threads, 128 queries/block, 512 blocks = 2 blocks/CU = 8 waves/SIMD.
// ---------------------------------------------------------------------------
__global__ __launch_bounds__(1024, 8) void knn_gather_prep_kernel(
    const float* __restrict__ xyz1, const float* __restrict__ xyz2,
    const float* __restrict__ feat2, ushort* __restrict__ interpB,
    const float* __restrict__ W1, ushort* __restrict__ W1t,
    const float* __restrict__ W2, ushort* __restrict__ W2pack)
{
    __shared__ float4 sp[SS];                     // 32 KB
    __shared__ int   sIdx[128][3];
    __shared__ float sW[128][3];

    const int tid   = threadIdx.x;
    const int b     = blockIdx.x & 7;             // XCD-aligned batch
    const int chunk = blockIdx.x >> 3;            // 0..63
    const int qbase = chunk << 7;                 // 128 queries per block

    const float* x2 = xyz2 + (size_t)b * SS * 3;
    for (int i = tid; i < SS; i += 1024) {
        float x = x2[i*3+0], y = x2[i*3+1], z = x2[i*3+2];
        sp[i] = make_float4(-2.f*x, -2.f*y, -2.f*z, x*x + y*y + z*z);
    }

    // ---- folded weights prep: one guarded element per thread --------------
    {
        const int idx = blockIdx.x * 1024 + tid;  // 0..524287
        const int n1 = KIN * OUTC;                // 98304
        if (idx < n1) {
            int n = idx / KIN, k = idx - n * KIN;
            W1t[idx] = f2bf(W1[(size_t)k * OUTC + n]);
        } else if (idx < n1 + OUTC * OUTC) {
            int o = idx - n1;
            int e = o & 7, lane = (o >> 3) & 63, j = (o >> 9) & 3;
            int wc = (o >> 11) & 3, s = o >> 13;
            int n = wc * 64 + j * 16 + (lane & 15);
            int k = s * 32 + (lane >> 4) * 8 + e;
            W2pack[o] = f2bf(W2[(size_t)k * OUTC + n]);
        }
    }
    __syncthreads();

    const int g = tid >> 4;                       // 0..63 (query pair)
    const int l = tid & 15;                       // lane within query
    const int qa = qbase + g * 2;

    const float* qp = xyz1 + ((size_t)b * NN + qa) * 3;
    float px[2] = {qp[0], qp[3]};
    float py[2] = {qp[1], qp[4]};
    float pz[2] = {qp[2], qp[5]};

    // ---------------- pass 1: top-3 values, branchless ----------------
    float c0[2], c1[2], c2[2];
#pragma unroll
    for (int qi = 0; qi < 2; ++qi) { c0[qi] = c1[qi] = c2[qi] = 1e30f; }

    for (int jj = 0; jj < 128; jj += 4) {
        float4 P[4];
#pragma unroll
        for (int u = 0; u < 4; ++u) P[u] = sp[((jj + u) << 4) + l];
#pragma unroll
        for (int u = 0; u < 4; ++u) {
#pragma unroll
            for (int qi = 0; qi < 2; ++qi) {
                float f = fmaf(px[qi], P[u].x,
                          fmaf(py[qi], P[u].y,
                          fmaf(pz[qi], P[u].z, P[u].w)));
                c2[qi] = med3(f, c1[qi], c2[qi]);
                c1[qi] = med3(f, c0[qi], c1[qi]);
                c0[qi] = fminf(f, c0[qi]);
            }
        }
    }

    // value-merge across the 16-lane group (multiset union top-3)
#pragma unroll
    for (int m = 1; m <= 8; m <<= 1) {
#pragma unroll
        for (int qi = 0; qi < 2; ++qi) {
            float b0 = __shfl_xor(c0[qi], m);
            float b1 = __shfl_xor(c1[qi], m);
            float b2 = __shfl_xor(c2[qi], m);
            float bv[3] = {b0, b1, b2};
#pragma unroll
            for (int e = 0; e < 3; ++e) {
                float d = bv[e];
                c2[qi] = med3(d, c1[qi], c2[qi]);
                c1[qi] = med3(d, c0[qi], c1[qi]);
                c0[qi] = fminf(d, c0[qi]);
            }
        }
    }
    const float t0 = c2[0], t1 = c2[1];           // exact 3rd-smallest scores

    // ---------------- pass 2: index recovery (rare inserts) ----------------
    float e0[2], e1[2], e2[2];
    int   i0[2], i1[2], i2[2];
#pragma unroll
    for (int qi = 0; qi < 2; ++qi) {
        e0[qi] = e1[qi] = e2[qi] = 1e30f;
        i0[qi] = i1[qi] = i2[qi] = 0x3fffffff;
    }

    for (int jj = 0; jj < 128; jj += 4) {
        float4 P[4];
#pragma unroll
        for (int u = 0; u < 4; ++u) P[u] = sp[((jj + u) << 4) + l];
#pragma unroll
        for (int u = 0; u < 4; ++u) {
            const int s = ((jj + u) << 4) + l;
#pragma unroll
            for (int qi = 0; qi < 2; ++qi) {
                float f = fmaf(px[qi], P[u].x,
                          fmaf(py[qi], P[u].y,
                          fmaf(pz[qi], P[u].z, P[u].w)));
                float tq = qi ? t1 : t0;
                if (f <= tq) {                     // ~3 hits per query total
                    bool lt2 = (f < e2[qi]) || (f == e2[qi] && s < i2[qi]);
                    if (lt2) {
                        bool lt1 = (f < e1[qi]) || (f == e1[qi] && s < i1[qi]);
                        bool lt0 = (f < e0[qi]) || (f == e0[qi] && s < i0[qi]);
                        e2[qi] = lt1 ? e1[qi] : f;  i2[qi] = lt1 ? i1[qi] : s;
                        e1[qi] = lt0 ? e0[qi] : (lt1 ? f : e1[qi]);
                        i1[qi] = lt0 ? i0[qi] : (lt1 ? s : i1[qi]);
                        e0[qi] = lt0 ? f : e0[qi];  i0[qi] = lt0 ? s : i0[qi];
                    }
                }
            }
        }
    }

    // lex merge across the 16-lane group
#pragma unroll
    for (int m = 1; m <= 8; m <<= 1) {
#pragma unroll
        for (int qi = 0; qi < 2; ++qi) {
            float ob0 = __shfl_xor(e0[qi], m), ob1 = __shfl_xor(e1[qi], m), ob2 = __shfl_xor(e2[qi], m);
            int   oj0 = __shfl_xor(i0[qi], m), oj1 = __shfl_xor(i1[qi], m), oj2 = __shfl_xor(i2[qi], m);
            float dv[3] = {ob0, ob1, ob2}; int iv[3] = {oj0, oj1, oj2};
#pragma unroll
            for (int e = 0; e < 3; ++e) {
                float d = dv[e]; int s = iv[e];
                bool lt2 = (d < e2[qi]) || (d == e2[qi] && s < i2[qi]);
                if (lt2) {
                    bool lt1 = (d < e1[qi]) || (d == e1[qi] && s < i1[qi]);
                    bool lt0 = (d < e0[qi]) || (d == e0[qi] && s < i0[qi]);
                    e2[qi] = lt1 ? e1[qi] : d;  i2[qi] = lt1 ? i1[qi] : s;
                    e1[qi] = lt0 ? e0[qi] : (lt1 ? d : e1[qi]);
                    i1[qi] = lt0 ? i0[qi] : (lt1 ? s : i1[qi]);
                    e0[qi] = lt0 ? d : e0[qi];  i0[qi] = lt0 ? s : i0[qi];
                }
            }
        }
    }

    if (l == 0) {
#pragma unroll
        for (int qi = 0; qi < 2; ++qi) {
            float nx = px[qi], ny = py[qi], nz = pz[qi];
            float n1 = nx*nx + ny*ny + nz*nz;
            float d0 = sqrtf(fmaxf(n1 + e0[qi], 0.f));
            float d1 = sqrtf(fmaxf(n1 + e1[qi], 0.f));
            float d2s = sqrtf(fmaxf(n1 + e2[qi], 0.f));
            float w0 = 1.f / fmaxf(d0, 1e-10f);
            float w1 = 1.f / fmaxf(d1, 1e-10f);
            float w2 = 1.f / fmaxf(d2s, 1e-10f);
            float wsum = w0 + w1 + w2;
            int qq = g * 2 + qi;
            sIdx[qq][0] = i0[qi]; sIdx[qq][1] = i1[qi]; sIdx[qq][2] = i2[qi];
            sW[qq][0] = w0 / wsum; sW[qq][1] = w1 / wsum; sW[qq][2] = w2 / wsum;
        }
    }
    __syncthreads();

    // gather phase: wave wid handles queries wid, wid+16, ... (coalesced rows)
    const int wid = tid >> 6, lane = tid & 63;
    for (int qq = wid; qq < 128; qq += 16) {
        int a0 = sIdx[qq][0], a1 = sIdx[qq][1], a2 = sIdx[qq][2];
        float w0 = sW[qq][0], w1 = sW[qq][1], w2 = sW[qq][2];
        const float4* r0 = (const float4*)(feat2 + ((size_t)b * SS + a0) * C2C);
        const float4* r1 = (const float4*)(feat2 + ((size_t)b * SS + a1) * C2C);
        const float4* r2 = (const float4*)(feat2 + ((size_t)b * SS + a2) * C2C);
        float4 v0 = r0[lane], v1 = r1[lane], v2 = r2[lane];
        ushort4 o;
        o.x = f2bf(w0*v0.x + w1*v1.x + w2*v2.x);
        o.y = f2bf(w0*v0.y + w1*v1.y + w2*v2.y);
        o.z = f2bf(w0*v0.z + w1*v1.z + w2*v2.z);
        o.w = f2bf(w0*v0.w + w1*v1.w + w2*v2.w);
        *(ushort4*)(interpB + ((size_t)b * NN + qbase + qq) * C2C + lane * 4) = o;
    }
}

// ---------------------------------------------------------------------------
// FUSED two-layer MFMA GEMM (EXACT r16, measured best):
//   out = relu(relu([feat1|interpB]@W1^T + b1)@W2^T + b2), H in LDS only.
// Phase 1: dbuf staged A+W1t (1 barrier/K-step). Phase 2: register-B from
// W2pack (contiguous 1KB bursts, 1-step prefetch), barrier-free.
// ---------------------------------------------------------------------------
#define GBM 128
#define GBN 256
#define GBK 32

__device__ __forceinline__ void gld_lds16(const void* g, void* l) {
    __builtin_amdgcn_global_load_lds(
        (const __attribute__((address_space(1))) void*)g,
        (__attribute__((address_space(3))) void*)l, 16, 0, 0);
}

__global__ __launch_bounds__(512, 4) void gemm_fused(
    const float* __restrict__ feat1,
    const ushort* __restrict__ interpB,
    const ushort* __restrict__ W1t, const float* __restrict__ b1,
    const ushort* __restrict__ W2pack, const float* __restrict__ b2,
    float* __restrict__ out)
{
    __shared__ ushort pool[GBM * 256];   // 64 KB: phase1 dbuf (2x24KB); then H

    const int tid  = threadIdx.x;
    const int lane = tid & 63;
    const int wid  = tid >> 6;           // 0..7
    const int m0   = blockIdx.x * GBM;
    const int wr   = wid >> 2;           // 0..1
    const int wc   = wid & 3;            // 0..3

    const int rsub = lane >> 2;                    // 0..15 (row in 16-row chunk)
    const int slot = lane & 3;                     // 0..3  (8-ushort slot)
    const int csub = slot * 8;                     // linear LDS slot offset
    const int usw  = (slot ^ (rsub & 3)) * 8;      // swizzled SOURCE slot offset

    const int kgrp = (lane >> 4) * 8;
    const int rl   = lane & 15;
    const int ksw  = kgrp ^ ((rl & 3) << 3);       // swizzled read slot
    const int cl   = lane & 15;
    const int rgrp = (lane >> 4) * 4;

    // stage one K-step of A (8 chunks) + W1t (16 chunks) into buffer `buf`.
    auto stageAB = [&](int k0, int buf) {
        ushort* sAb = pool + buf * 12288;          // 8KB A
        ushort* sBb = sAb + 4096;                  // 16KB B
#pragma unroll
        for (int c = 0; c < 3; ++c) {
            const int cid = wid * 3 + c;           // 0..23
            if (cid < 8) {
                const int r = m0 + cid * 16 + rsub;
                if (k0 < C1C) {
                    const float* src = feat1 + (size_t)r * C1C + k0 + usw;
                    float4 u = ((const float4*)src)[0];
                    float4 v = ((const float4*)src)[1];
                    ushortx8 t;
                    t[0] = f2bf(u.x); t[1] = f2bf(u.y); t[2] = f2bf(u.z); t[3] = f2bf(u.w);
                    t[4] = f2bf(v.x); t[5] = f2bf(v.y); t[6] = f2bf(v.z); t[7] = f2bf(v.w);
                    *(ushortx8*)&sAb[cid * 512 + rsub * 32 + csub] = t;
                } else {
                    gld_lds16(interpB + (size_t)r * C2C + (k0 - C1C) + usw, &sAb[cid * 512]);
                }
            } else {
                const int bi = cid - 8;
                const int r = bi * 16 + rsub;
                gld_lds16(W1t + (size_t)r * KIN + k0 + usw, &sBb[bi * 512]);
            }
        }
    };

    // ---------------- phase 1: acc1 = A @ W1t^T (double-buffered) ----------
    f32x4 acc1[4][4];
#pragma unroll
    for (int i = 0; i < 4; ++i)
#pragma unroll
        for (int j = 0; j < 4; ++j) acc1[i][j] = (f32x4){0.f, 0.f, 0.f, 0.f};

    int cur = 0;
    stageAB(0, 0);
    for (int k0 = 0; k0 < KIN; k0 += GBK) {
        __syncthreads();                 // stage(k0->cur) done; prev reads done
        if (k0 + GBK < KIN) stageAB(k0 + GBK, cur ^ 1);

        const ushort* sAb = pool + cur * 12288;
        const ushort* sBb = sAb + 4096;
        short8 af[4], bf[4];
#pragma unroll
        for (int i = 0; i < 4; ++i) {
            af[i] = *(const short8*)&sAb[(wr * 64 + i * 16 + rl) * GBK + ksw];
            bf[i] = *(const short8*)&sBb[(wc * 64 + i * 16 + rl) * GBK + ksw];
        }
#pragma unroll
        for (int i = 0; i < 4; ++i)
#pragma unroll
            for (int j = 0; j < 4; ++j)
                acc1[i][j] = __builtin_amdgcn_mfma_f32_16x16x32_bf16(
                    af[i], bf[j], acc1[i][j], 0, 0, 0);
        cur ^= 1;
    }
    __syncthreads();                     // all phase-1 LDS reads done (pool reuse)

    // issue phase-2 first B-frags early (hide L2 latency under H writes)
    short8 bfc[4], bfn[4];
#pragma unroll
    for (int j = 0; j < 4; ++j)
        bfc[j] = *(const short8*)&W2pack[(size_t)(0 * 16 + wc * 4 + j) * 512 + lane * 8];

    // ---------------- transition: H = relu(acc1+b1) -> LDS (bf16) ----------
#pragma unroll
    for (int j = 0; j < 4; ++j) {
        const int c = wc * 64 + j * 16 + cl;
        const float bv = b1[c];
        const int u = c >> 3, sub = c & 7;
#pragma unroll
        for (int i = 0; i < 4; ++i) {
#pragma unroll
            for (int rr = 0; rr < 4; ++rr) {
                const int r = wr * 64 + i * 16 + rgrp + rr;
                const float v = fmaxf(acc1[i][j][rr] + bv, 0.f);
                pool[r * 256 + ((u ^ (r & 31)) << 3) + sub] = f2bf(v);
            }
        }
    }
    __syncthreads();                     // H complete

    // ---------------- phase 2: out = relu(H @ W2^T + b2), barrier-free -----
    f32x4 acc2[4][4];
#pragma unroll
    for (int i = 0; i < 4; ++i)
#pragma unroll
        for (int j = 0; j < 4; ++j) acc2[i][j] = (f32x4){0.f, 0.f, 0.f, 0.f};

    for (int s = 0; s < 8; ++s) {
        if (s < 7) {
#pragma unroll
            for (int j = 0; j < 4; ++j)
                bfn[j] = *(const short8*)&W2pack[(size_t)((s + 1) * 16 + wc * 4 + j) * 512 + lane * 8];
        }
        const int ub = s * 4 + (lane >> 4);        // H unit index 0..31
        short8 af[4];
#pragma unroll
        for (int i = 0; i < 4; ++i) {
            const int r = wr * 64 + i * 16 + rl;
            af[i] = *(const short8*)&pool[r * 256 + ((ub ^ (r & 31)) << 3)];
        }
#pragma unroll
        for (int i = 0; i < 4; ++i)
#pragma unroll
            for (int j = 0; j < 4; ++j)
                acc2[i][j] = __builtin_amdgcn_mfma_f32_16x16x32_bf16(
                    af[i], bfc[j], acc2[i][j], 0, 0, 0);
#pragma unroll
        for (int j = 0; j < 4; ++j) bfc[j] = bfn[j];
    }

    // ---------------- epilogue: bias + relu -> f32 out ---------------------
#pragma unroll
    for (int j = 0; j < 4; ++j) {
        const int col = wc * 64 + j * 16 + cl;
        const float bv = b2[col];
#pragma unroll
        for (int i = 0; i < 4; ++i) {
            const int rowb = m0 + wr * 64 + i * 16 + rgrp;
#pragma unroll
            for (int rr = 0; rr < 4; ++rr) {
                out[(size_t)(rowb + rr) * OUTC + col] =
                    fmaxf(acc2[i][j][rr] + bv, 0.f);
            }
        }
    }
}

// ---------------------------------------------------------------------------
// ws layout (bytes): interpB 33.5M @0 | W1t @33554432 | W2pack @33751040
// ---------------------------------------------------------------------------
extern "C" void kernel_launch(void* const* d_in, const int* in_sizes, int n_in,
                              void* d_out, int out_size, void* d_ws, size_t ws_size,
                              hipStream_t stream) {
    const float* xyz1  = (const float*)d_in[0];
    const float* xyz2  = (const float*)d_in[1];
    const float* feat1 = (const float*)d_in[2];
    const float* feat2 = (const float*)d_in[3];
    const float* W1    = (const float*)d_in[4];
    const float* b1    = (const float*)d_in[5];
    const float* W2    = (const float*)d_in[6];
    const float* b2    = (const float*)d_in[7];
    float* out = (float*)d_out;

    char* ws = (char*)d_ws;
    ushort* interpB = (ushort*)(ws);
    ushort* W1t     = (ushort*)(ws + 33554432);
    ushort* W2pack  = (ushort*)(ws + 33751040);

    const int M = BB * NN;  // 65536

    knn_gather_prep_kernel<<<512, 1024, 0, stream>>>(xyz1, xyz2, feat2, interpB,
                                                     W1, W1t, W2, W2pack);

    gemm_fused<<<M / GBM, 512, 0, stream>>>(feat1, interpB,
                                            W1t, b1, W2pack, b2, out);
}

// Round 20
// 97.718 us; speedup vs baseline: 1.1734x; 1.0440x over previous
//
#include <hip/hip_runtime.h>
#include <hip/hip_bf16.h>

// Problem constants: B=8, N=8192, S=2048, C1=128, C2=256, OUT=256
#define BB   8
#define NN   8192
#define SS   2048
#define C1C  128
#define C2C  256
#define KIN  384
#define OUTC 256

typedef __attribute__((ext_vector_type(4))) float f32x4;
typedef __attribute__((ext_vector_type(8))) short short8;
typedef __attribute__((ext_vector_type(8))) unsigned short ushortx8;

__device__ __forceinline__ ushort f2bf(float v) {
    __hip_bfloat16 h = __float2bfloat16(v);
    return __builtin_bit_cast(ushort, h);
}

__device__ __forceinline__ float med3(float a, float b, float c) {
    return __builtin_amdgcn_fmed3f(a, b, c);
}

// ---------------------------------------------------------------------------
// Fused 3-NN scan + gather + weights prep (r19 structure, measured 66us).
// Only change vs r19: prep fills W1pack (fragment-packed, same formula as
// W2pack — verified since r16 passes) instead of W1t.
// 1024 threads, 128 queries/block, 512 blocks = 2 blocks/CU = 8 waves/SIMD.
// ---------------------------------------------------------------------------
__global__ __launch_bounds__(1024, 8) void knn_gather_prep_kernel(
    const float* __restrict__ xyz1, const float* __restrict__ xyz2,
    const float* __restrict__ feat2, ushort* __restrict__ interpB,
    const float* __restrict__ W1, ushort* __restrict__ W1pack,
    const float* __restrict__ W2, ushort* __restrict__ W2pack)
{
    __shared__ float4 sp[SS];                     // 32 KB
    __shared__ int   sIdx[128][3];
    __shared__ float sW[128][3];

    const int tid   = threadIdx.x;
    const int b     = blockIdx.x & 7;             // XCD-aligned batch
    const int chunk = blockIdx.x >> 3;            // 0..63
    const int qbase = chunk << 7;                 // 128 queries per block

    const float* x2 = xyz2 + (size_t)b * SS * 3;
    for (int i = tid; i < SS; i += 1024) {
        float x = x2[i*3+0], y = x2[i*3+1], z = x2[i*3+2];
        sp[i] = make_float4(-2.f*x, -2.f*y, -2.f*z, x*x + y*y + z*z);
    }

    // ---- folded weights prep: one guarded element per thread --------------
    // W1pack/W2pack layout: [s][wc][j][lane][e], elem = W[k][n] with
    // n = wc*64+j*16+(lane&15), k = s*32+(lane>>4)*8+e.
    {
        const int idx = blockIdx.x * 1024 + tid;  // 0..524287
        const int n1 = 12 * 16 * 512;             // 98304 (W1pack, s=0..11)
        if (idx < n1) {
            int o = idx;
            int e = o & 7, lane = (o >> 3) & 63, j = (o >> 9) & 3;
            int wc = (o >> 11) & 3, s = o >> 13;
            int n = wc * 64 + j * 16 + (lane & 15);
            int k = s * 32 + (lane >> 4) * 8 + e;
            W1pack[o] = f2bf(W1[(size_t)k * OUTC + n]);
        } else if (idx < n1 + OUTC * OUTC) {
            int o = idx - n1;
            int e = o & 7, lane = (o >> 3) & 63, j = (o >> 9) & 3;
            int wc = (o >> 11) & 3, s = o >> 13;
            int n = wc * 64 + j * 16 + (lane & 15);
            int k = s * 32 + (lane >> 4) * 8 + e;
            W2pack[o] = f2bf(W2[(size_t)k * OUTC + n]);
        }
    }
    __syncthreads();

    const int g = tid >> 4;                       // 0..63 (query pair)
    const int l = tid & 15;                       // lane within query
    const int qa = qbase + g * 2;

    const float* qp = xyz1 + ((size_t)b * NN + qa) * 3;
    float px[2] = {qp[0], qp[3]};
    float py[2] = {qp[1], qp[4]};
    float pz[2] = {qp[2], qp[5]};

    // ---------------- pass 1: top-3 values, branchless ----------------
    float c0[2], c1[2], c2[2];
#pragma unroll
    for (int qi = 0; qi < 2; ++qi) { c0[qi] = c1[qi] = c2[qi] = 1e30f; }

    for (int jj = 0; jj < 128; jj += 4) {
        float4 P[4];
#pragma unroll
        for (int u = 0; u < 4; ++u) P[u] = sp[((jj + u) << 4) + l];
#pragma unroll
        for (int u = 0; u < 4; ++u) {
#pragma unroll
            for (int qi = 0; qi < 2; ++qi) {
                float f = fmaf(px[qi], P[u].x,
                          fmaf(py[qi], P[u].y,
                          fmaf(pz[qi], P[u].z, P[u].w)));
                c2[qi] = med3(f, c1[qi], c2[qi]);
                c1[qi] = med3(f, c0[qi], c1[qi]);
                c0[qi] = fminf(f, c0[qi]);
            }
        }
    }

    // value-merge across the 16-lane group (multiset union top-3)
#pragma unroll
    for (int m = 1; m <= 8; m <<= 1) {
#pragma unroll
        for (int qi = 0; qi < 2; ++qi) {
            float b0 = __shfl_xor(c0[qi], m);
            float b1 = __shfl_xor(c1[qi], m);
            float b2 = __shfl_xor(c2[qi], m);
            float bv[3] = {b0, b1, b2};
#pragma unroll
            for (int e = 0; e < 3; ++e) {
                float d = bv[e];
                c2[qi] = med3(d, c1[qi], c2[qi]);
                c1[qi] = med3(d, c0[qi], c1[qi]);
                c0[qi] = fminf(d, c0[qi]);
            }
        }
    }
    const float t0 = c2[0], t1 = c2[1];           // exact 3rd-smallest scores

    // ---------------- pass 2: index recovery (rare inserts) ----------------
    float e0[2], e1[2], e2[2];
    int   i0[2], i1[2], i2[2];
#pragma unroll
    for (int qi = 0; qi < 2; ++qi) {
        e0[qi] = e1[qi] = e2[qi] = 1e30f;
        i0[qi] = i1[qi] = i2[qi] = 0x3fffffff;
    }

    for (int jj = 0; jj < 128; jj += 4) {
        float4 P[4];
#pragma unroll
        for (int u = 0; u < 4; ++u) P[u] = sp[((jj + u) << 4) + l];
#pragma unroll
        for (int u = 0; u < 4; ++u) {
            const int s = ((jj + u) << 4) + l;
#pragma unroll
            for (int qi = 0; qi < 2; ++qi) {
                float f = fmaf(px[qi], P[u].x,
                          fmaf(py[qi], P[u].y,
                          fmaf(pz[qi], P[u].z, P[u].w)));
                float tq = qi ? t1 : t0;
                if (f <= tq) {                     // ~3 hits per query total
                    bool lt2 = (f < e2[qi]) || (f == e2[qi] && s < i2[qi]);
                    if (lt2) {
                        bool lt1 = (f < e1[qi]) || (f == e1[qi] && s < i1[qi]);
                        bool lt0 = (f < e0[qi]) || (f == e0[qi] && s < i0[qi]);
                        e2[qi] = lt1 ? e1[qi] : f;  i2[qi] = lt1 ? i1[qi] : s;
                        e1[qi] = lt0 ? e0[qi] : (lt1 ? f : e1[qi]);
                        i1[qi] = lt0 ? i0[qi] : (lt1 ? s : i1[qi]);
                        e0[qi] = lt0 ? f : e0[qi];  i0[qi] = lt0 ? s : i0[qi];
                    }
                }
            }
        }
    }

    // lex merge across the 16-lane group
#pragma unroll
    for (int m = 1; m <= 8; m <<= 1) {
#pragma unroll
        for (int qi = 0; qi < 2; ++qi) {
            float ob0 = __shfl_xor(e0[qi], m), ob1 = __shfl_xor(e1[qi], m), ob2 = __shfl_xor(e2[qi], m);
            int   oj0 = __shfl_xor(i0[qi], m), oj1 = __shfl_xor(i1[qi], m), oj2 = __shfl_xor(i2[qi], m);
            float dv[3] = {ob0, ob1, ob2}; int iv[3] = {oj0, oj1, oj2};
#pragma unroll
            for (int e = 0; e < 3; ++e) {
                float d = dv[e]; int s = iv[e];
                bool lt2 = (d < e2[qi]) || (d == e2[qi] && s < i2[qi]);
                if (lt2) {
                    bool lt1 = (d < e1[qi]) || (d == e1[qi] && s < i1[qi]);
                    bool lt0 = (d < e0[qi]) || (d == e0[qi] && s < i0[qi]);
                    e2[qi] = lt1 ? e1[qi] : d;  i2[qi] = lt1 ? i1[qi] : s;
                    e1[qi] = lt0 ? e0[qi] : (lt1 ? d : e1[qi]);
                    i1[qi] = lt0 ? i0[qi] : (lt1 ? s : i1[qi]);
                    e0[qi] = lt0 ? d : e0[qi];  i0[qi] = lt0 ? s : i0[qi];
                }
            }
        }
    }

    if (l == 0) {
#pragma unroll
        for (int qi = 0; qi < 2; ++qi) {
            float nx = px[qi], ny = py[qi], nz = pz[qi];
            float n1 = nx*nx + ny*ny + nz*nz;
            float d0 = sqrtf(fmaxf(n1 + e0[qi], 0.f));
            float d1 = sqrtf(fmaxf(n1 + e1[qi], 0.f));
            float d2s = sqrtf(fmaxf(n1 + e2[qi], 0.f));
            float w0 = 1.f / fmaxf(d0, 1e-10f);
            float w1 = 1.f / fmaxf(d1, 1e-10f);
            float w2 = 1.f / fmaxf(d2s, 1e-10f);
            float wsum = w0 + w1 + w2;
            int qq = g * 2 + qi;
            sIdx[qq][0] = i0[qi]; sIdx[qq][1] = i1[qi]; sIdx[qq][2] = i2[qi];
            sW[qq][0] = w0 / wsum; sW[qq][1] = w1 / wsum; sW[qq][2] = w2 / wsum;
        }
    }
    __syncthreads();

    // gather phase: wave wid handles queries wid, wid+16, ... (coalesced rows)
    const int wid = tid >> 6, lane = tid & 63;
    for (int qq = wid; qq < 128; qq += 16) {
        int a0 = sIdx[qq][0], a1 = sIdx[qq][1], a2 = sIdx[qq][2];
        float w0 = sW[qq][0], w1 = sW[qq][1], w2 = sW[qq][2];
        const float4* r0 = (const float4*)(feat2 + ((size_t)b * SS + a0) * C2C);
        const float4* r1 = (const float4*)(feat2 + ((size_t)b * SS + a1) * C2C);
        const float4* r2 = (const float4*)(feat2 + ((size_t)b * SS + a2) * C2C);
        float4 v0 = r0[lane], v1 = r1[lane], v2 = r2[lane];
        ushort4 o;
        o.x = f2bf(w0*v0.x + w1*v1.x + w2*v2.x);
        o.y = f2bf(w0*v0.y + w1*v1.y + w2*v2.y);
        o.z = f2bf(w0*v0.z + w1*v1.z + w2*v2.z);
        o.w = f2bf(w0*v0.w + w1*v1.w + w2*v2.w);
        *(ushort4*)(interpB + ((size_t)b * NN + qbase + qq) * C2C + lane * 4) = o;
    }
}

// ---------------------------------------------------------------------------
// FUSED two-layer MFMA GEMM, v6 = r16 + register-B in BOTH phases:
//   out = relu(relu([feat1|interpB]@W1^T + b1)@W2^T + b2), H in LDS only.
// Phase 1 (NEW): A-only LDS staging (1 chunk/wave, dbuf 2x8KB in pool),
// W1 B-frags register-loaded from W1pack (contiguous 1KB bursts, 1-step
// prefetch) — the exact transform that won in phase 2 (r16), applied to
// phase 1. Staging chunks/wave 3->1, LDS frag reads 8->4 per K-step.
// Phase 2: EXACT r16 (W2pack register-B, barrier-free).
// LDS: 64KB pool -> 2 blocks/CU. VGPR ~120 target (spill = abort).
// C/D mapping (verified r1+): col = lane&15, row = (lane>>4)*4 + reg.
// ---------------------------------------------------------------------------
#define GBM 128
#define GBN 256
#define GBK 32

__device__ __forceinline__ void gld_lds16(const void* g, void* l) {
    __builtin_amdgcn_global_load_lds(
        (const __attribute__((address_space(1))) void*)g,
        (__attribute__((address_space(3))) void*)l, 16, 0, 0);
}

__global__ __launch_bounds__(512, 4) void gemm_fused(
    const float* __restrict__ feat1,
    const ushort* __restrict__ interpB,
    const ushort* __restrict__ W1pack, const float* __restrict__ b1,
    const ushort* __restrict__ W2pack, const float* __restrict__ b2,
    float* __restrict__ out)
{
    __shared__ ushort pool[GBM * 256];   // 64 KB: phase1 A-dbuf (2x8KB); then H

    const int tid  = threadIdx.x;
    const int lane = tid & 63;
    const int wid  = tid >> 6;           // 0..7
    const int m0   = blockIdx.x * GBM;
    const int wr   = wid >> 2;           // 0..1
    const int wc   = wid & 3;            // 0..3

    const int rsub = lane >> 2;                    // 0..15 (row in 16-row chunk)
    const int slot = lane & 3;                     // 0..3  (8-ushort slot)
    const int csub = slot * 8;                     // linear LDS slot offset
    const int usw  = (slot ^ (rsub & 3)) * 8;      // swizzled SOURCE slot offset

    const int kgrp = (lane >> 4) * 8;
    const int rl   = lane & 15;
    const int ksw  = kgrp ^ ((rl & 3) << 3);       // swizzled read slot
    const int cl   = lane & 15;
    const int rgrp = (lane >> 4) * 4;

    // stage one K-step of A only: each wave stages its own 16-row chunk.
    auto stageA = [&](int k0, int buf) {
        ushort* sAb = pool + buf * 4096;           // 8KB buffer
        const int r = m0 + wid * 16 + rsub;
        if (k0 < C1C) {
            const float* src = feat1 + (size_t)r * C1C + k0 + usw;
            float4 u = ((const float4*)src)[0];
            float4 v = ((const float4*)src)[1];
            ushortx8 t;
            t[0] = f2bf(u.x); t[1] = f2bf(u.y); t[2] = f2bf(u.z); t[3] = f2bf(u.w);
            t[4] = f2bf(v.x); t[5] = f2bf(v.y); t[6] = f2bf(v.z); t[7] = f2bf(v.w);
            *(ushortx8*)&sAb[wid * 512 + rsub * 32 + csub] = t;
        } else {
            gld_lds16(interpB + (size_t)r * C2C + (k0 - C1C) + usw, &sAb[wid * 512]);
        }
    };

    // ---------------- phase 1: acc1 = A @ W1^T (A-dbuf + register B) -------
    f32x4 acc1[4][4];
#pragma unroll
    for (int i = 0; i < 4; ++i)
#pragma unroll
        for (int j = 0; j < 4; ++j) acc1[i][j] = (f32x4){0.f, 0.f, 0.f, 0.f};

    int cur = 0;
    stageA(0, 0);
    short8 bfc[4], bfn[4];
#pragma unroll
    for (int j = 0; j < 4; ++j)
        bfc[j] = *(const short8*)&W1pack[(size_t)(0 * 16 + wc * 4 + j) * 512 + lane * 8];

    for (int k0 = 0, s = 0; k0 < KIN; k0 += GBK, ++s) {
        __syncthreads();                 // stage(k0->cur) done; prev reads done
        if (k0 + GBK < KIN) {
            stageA(k0 + GBK, cur ^ 1);
#pragma unroll
            for (int j = 0; j < 4; ++j)
                bfn[j] = *(const short8*)&W1pack[(size_t)((s + 1) * 16 + wc * 4 + j) * 512 + lane * 8];
        }

        const ushort* sAb = pool + cur * 4096;
        short8 af[4];
#pragma unroll
        for (int i = 0; i < 4; ++i)
            af[i] = *(const short8*)&sAb[(wr * 64 + i * 16 + rl) * GBK + ksw];
#pragma unroll
        for (int i = 0; i < 4; ++i)
#pragma unroll
            for (int j = 0; j < 4; ++j)
                acc1[i][j] = __builtin_amdgcn_mfma_f32_16x16x32_bf16(
                    af[i], bfc[j], acc1[i][j], 0, 0, 0);
#pragma unroll
        for (int j = 0; j < 4; ++j) bfc[j] = bfn[j];
        cur ^= 1;
    }
    __syncthreads();                     // all phase-1 LDS reads done (pool reuse)

    // issue phase-2 first B-frags early (hide L2 latency under H writes)
#pragma unroll
    for (int j = 0; j < 4; ++j)
        bfc[j] = *(const short8*)&W2pack[(size_t)(0 * 16 + wc * 4 + j) * 512 + lane * 8];

    // ---------------- transition: H = relu(acc1+b1) -> LDS (bf16) ----------
#pragma unroll
    for (int j = 0; j < 4; ++j) {
        const int c = wc * 64 + j * 16 + cl;
        const float bv = b1[c];
        const int u = c >> 3, sub = c & 7;
#pragma unroll
        for (int i = 0; i < 4; ++i) {
#pragma unroll
            for (int rr = 0; rr < 4; ++rr) {
                const int r = wr * 64 + i * 16 + rgrp + rr;
                const float v = fmaxf(acc1[i][j][rr] + bv, 0.f);
                pool[r * 256 + ((u ^ (r & 31)) << 3) + sub] = f2bf(v);
            }
        }
    }
    __syncthreads();                     // H complete

    // ---------------- phase 2: out = relu(H @ W2^T + b2), barrier-free -----
    f32x4 acc2[4][4];
#pragma unroll
    for (int i = 0; i < 4; ++i)
#pragma unroll
        for (int j = 0; j < 4; ++j) acc2[i][j] = (f32x4){0.f, 0.f, 0.f, 0.f};

    for (int s = 0; s < 8; ++s) {
        if (s < 7) {
#pragma unroll
            for (int j = 0; j < 4; ++j)
                bfn[j] = *(const short8*)&W2pack[(size_t)((s + 1) * 16 + wc * 4 + j) * 512 + lane * 8];
        }
        const int ub = s * 4 + (lane >> 4);        // H unit index 0..31
        short8 af[4];
#pragma unroll
        for (int i = 0; i < 4; ++i) {
            const int r = wr * 64 + i * 16 + rl;
            af[i] = *(const short8*)&pool[r * 256 + ((ub ^ (r & 31)) << 3)];
        }
#pragma unroll
        for (int i = 0; i < 4; ++i)
#pragma unroll
            for (int j = 0; j < 4; ++j)
                acc2[i][j] = __builtin_amdgcn_mfma_f32_16x16x32_bf16(
                    af[i], bfc[j], acc2[i][j], 0, 0, 0);
#pragma unroll
        for (int j = 0; j < 4; ++j) bfc[j] = bfn[j];
    }

    // ---------------- epilogue: bias + relu -> f32 out ---------------------
#pragma unroll
    for (int j = 0; j < 4; ++j) {
        const int col = wc * 64 + j * 16 + cl;
        const float bv = b2[col];
#pragma unroll
        for (int i = 0; i < 4; ++i) {
            const int rowb = m0 + wr * 64 + i * 16 + rgrp;
#pragma unroll
            for (int rr = 0; rr < 4; ++rr) {
                out[(size_t)(rowb + rr) * OUTC + col] =
                    fmaxf(acc2[i][j][rr] + bv, 0.f);
            }
        }
    }
}

// ---------------------------------------------------------------------------
// ws layout (bytes): interpB 33.5M @0 | W1pack 192K @33554432
// | W2pack 128K @33751040
// ---------------------------------------------------------------------------
extern "C" void kernel_launch(void* const* d_in, const int* in_sizes, int n_in,
                              void* d_out, int out_size, void* d_ws, size_t ws_size,
                              hipStream_t stream) {
    const float* xyz1  = (const float*)d_in[0];
    const float* xyz2  = (const float*)d_in[1];
    const float* feat1 = (const float*)d_in[2];
    const float* feat2 = (const float*)d_in[3];
    const float* W1    = (const float*)d_in[4];
    const float* b1    = (const float*)d_in[5];
    const float* W2    = (const float*)d_in[6];
    const float* b2    = (const float*)d_in[7];
    float* out = (float*)d_out;

    char* ws = (char*)d_ws;
    ushort* interpB = (ushort*)(ws);
    ushort* W1pack  = (ushort*)(ws + 33554432);
    ushort* W2pack  = (ushort*)(ws + 33751040);

    const int M = BB * NN;  // 65536

    knn_gather_prep_kernel<<<512, 1024, 0, stream>>>(xyz1, xyz2, feat2, interpB,
                                                     W1, W1pack, W2, W2pack);

    gemm_fused<<<M / GBM, 512, 0, stream>>>(feat1, interpB,
                                            W1pack, b1, W2pack, b2, out);
}